// Round 15
// baseline (228.003 us; speedup 1.0000x reference)
//
#include <hip/hip_runtime.h>
#include <hip/hip_bf16.h>

// VectorQuantize: B=4, N=2048, DIM=256, HEADS=4, CODEBOOK=8192, HD=64
// Established (R0-R14): inputs fp32, output fp32 (quantize ++ indices-as-floats).
// fp16 2-level split (absmax 0 since R10): x ~ x0 + x1/4096, 3 MFMA terms,
// score ordering == fp32 argmin ordering (error ~2^-24).
// R14 (barrier-free global streaming): CLEAN (WRITE 1MB, VGPR 76, LDS 0) at
// 145us — but grid 512 = 2 blocks/CU capped occupancy at 22.5% again.
// R15: NPART=8, 1-WAVE blocks (64 thr, grid 4096 — no LDS/barriers so blocks
// are pure wave containers; HW packs to the register limit), and hoisted-ZERO
// acc init (first MFMA of each chain reads a loop-invariant zero C; ycn added
// in the epilogue) — kills 32 v_mov/iter.

#define HEADS    4
#define CODEBOOK 8192
#define HD       64
#define BQ       8192                  // queries per head = B*N
#define QOFF     (4 * 2048 * 256)      // quantize FLOAT elements in d_out
#define NPART    8
#define CPART    (CODEBOOK / NPART)    // 1024 codes per partition
#define RSCALE   4096.0f               // residual scale (2^12)
#define RINV     (1.0f / 4096.0f)

typedef _Float16 f16x8 __attribute__((ext_vector_type(8)));
typedef float    f32x4 __attribute__((ext_vector_type(4)));

__device__ _Float16 g_e0[HEADS * CODEBOOK * HD];  // split level 0 (4 MB)
__device__ _Float16 g_e1[HEADS * CODEBOOK * HD];  // split level 1 (x4096)
__device__ float    g_y2n[HEADS * CODEBOOK];      // -0.5*||e||^2 (exact fp32)
__device__ float    g_pval[NPART][HEADS * BQ];    // per-partition best (max score)
__device__ int      g_pidx[NPART][HEADS * BQ];    // per-partition best index

// split fp32 -> 2 fp16 levels: f ~= (float)h0 + (float)h1 / 4096, |err|<=2^-24|f|
__device__ inline void split2(float f, _Float16& h0, _Float16& h1) {
    h0 = (_Float16)f;
    float r = f - (float)h0;
    h1 = (_Float16)(r * RSCALE);
}

// ---------------- kernel 0: pre-split codebook + y2 ------------------------
__global__ __launch_bounds__(256) void prep_kernel(const float* __restrict__ embed) {
    int gid = blockIdx.x * 256 + threadIdx.x;     // 8-float granule id
    const float* p = embed + (size_t)gid * 8;
    float4 u = *reinterpret_cast<const float4*>(p);
    float4 w = *reinterpret_cast<const float4*>(p + 4);
    float f[8] = {u.x, u.y, u.z, u.w, w.x, w.y, w.z, w.w};
    f16x8 v0, v1;
    float ss = 0.f;
#pragma unroll
    for (int j = 0; j < 8; j++) {
        _Float16 h0, h1;
        split2(f[j], h0, h1);
        v0[j] = h0; v1[j] = h1;
        ss = fmaf(f[j], f[j], ss);
    }
    *reinterpret_cast<f16x8*>(g_e0 + (size_t)gid * 8) = v0;
    *reinterpret_cast<f16x8*>(g_e1 + (size_t)gid * 8) = v1;
#pragma unroll
    for (int off = 4; off >= 1; off >>= 1) ss += __shfl_xor(ss, off, 8);
    if ((threadIdx.x & 7) == 0) g_y2n[gid >> 3] = -0.5f * ss;
}

// ---------------- kernel 1: barrier-free split-fp16 MFMA + argmax ----------
// grid = 4096 one-wave blocks; bid&7 -> XCD, head = (bid&7)>>1 (each XCD works
// one head's 2MB planes -> L2-resident); idx = ((bid>>3)<<1)|(bid&1) in
// 0..1023: part = idx&7, wq = idx>>3 (0..127). Wave owns 64 queries (4 pinned
// A row-tiles) and streams its 1024-code partition from global in 16-code
// steps: 4 b128 loads + 24 MFMA + argmax. No LDS, no __syncthreads.
// MFMA 16x16x32_f16 layouts (HW-verified):
//   A: lane -> A[m=lane&15][k=quad*8+j];  B: lane -> B[k=quad*8+j][n=lane&15]
//   C: lane -> col=lane&15, row=quad*4+reg
__global__ __launch_bounds__(64, 2) void dist_kernel(const float* __restrict__ x) {
    const int bid  = blockIdx.x;
    const int head = (bid & 7) >> 1;
    const int idx  = ((bid >> 3) << 1) | (bid & 1);
    const int part = idx & 7;
    const int wq   = idx >> 3;                    // 0..127
    const int lane = threadIdx.x;                 // 0..63
    const int col  = lane & 15;
    const int quad = lane >> 4;

    const int qbase = wq * 64;                    // this wave's 64 queries
    const int cbase = part * CPART;

    // A fragments a[rowtile][level][khalf], split once from fp32 x
    f16x8 a[4][2][2];
#pragma unroll
    for (int rt = 0; rt < 4; rt++) {
#pragma unroll
        for (int kh = 0; kh < 2; kh++) {
            const float* p = x + ((size_t)(qbase + rt * 16 + col) * 256 + head * 64 + kh * 32 + quad * 8);
#pragma unroll
            for (int j = 0; j < 8; j++) {
                _Float16 h0, h1;
                split2(p[j], h0, h1);
                a[rt][0][kh][j] = h0;
                a[rt][1][kh][j] = h1;
            }
        }
    }

    // B stream bases: lane reads row (cc+col), 16B granule quad of each 64B half
    const size_t pb  = ((size_t)head * CODEBOOK + cbase) * HD;
    const _Float16* p0 = g_e0 + pb + (size_t)col * HD + quad * 8;
    const _Float16* p1 = g_e1 + pb + (size_t)col * HD + quad * 8;
    const float*    py = g_y2n + head * CODEBOOK + cbase + col;

    float bv[4][4]; int bc[4][4];
#pragma unroll
    for (int rt = 0; rt < 4; rt++)
#pragma unroll
        for (int r = 0; r < 4; r++) { bv[rt][r] = -3.4e38f; bc[rt][r] = 0; }

    const f32x4 ZERO = {0.f, 0.f, 0.f, 0.f};      // loop-invariant C operand

#pragma unroll 2
    for (int cc = 0; cc < CPART; cc += 16) {
        const size_t o = (size_t)cc * HD;
        f16x8 b00 = *reinterpret_cast<const f16x8*>(p0 + o);        // lvl0, k 0..31
        f16x8 b01 = *reinterpret_cast<const f16x8*>(p0 + o + 32);   // lvl0, k 32..63
        f16x8 b10 = *reinterpret_cast<const f16x8*>(p1 + o);        // lvl1, k 0..31
        f16x8 b11 = *reinterpret_cast<const f16x8*>(p1 + o + 32);   // lvl1, k 32..63
        const float ycn = py[cc];                                   // -0.5*||e_c||^2
        const int   c   = cc + col;

#pragma unroll
        for (int rt = 0; rt < 4; rt++) {
            // chains start from the hoisted ZERO (C is read-only; no per-iter movs)
            f32x4 aA = __builtin_amdgcn_mfma_f32_16x16x32_f16(a[rt][0][0], b00, ZERO, 0, 0, 0);
            f32x4 aB = __builtin_amdgcn_mfma_f32_16x16x32_f16(a[rt][0][0], b10, ZERO, 0, 0, 0);
            aA = __builtin_amdgcn_mfma_f32_16x16x32_f16(a[rt][0][1], b01, aA, 0, 0, 0);
            aB = __builtin_amdgcn_mfma_f32_16x16x32_f16(a[rt][1][0], b00, aB, 0, 0, 0);
            aB = __builtin_amdgcn_mfma_f32_16x16x32_f16(a[rt][0][1], b11, aB, 0, 0, 0);
            aB = __builtin_amdgcn_mfma_f32_16x16x32_f16(a[rt][1][1], b01, aB, 0, 0, 0);
#pragma unroll
            for (int r = 0; r < 4; r++) {
                float sv = fmaf(aB[r], RINV, aA[r]) + ycn;   // xy - 0.5||e||^2
                if (sv > bv[rt][r]) { bv[rt][r] = sv; bc[rt][r] = c; }
            }
        }
    }

    // reduce across 16 column slots; lexicographic (max val, min idx) =
    // np first-argmax tie-break
#pragma unroll
    for (int rt = 0; rt < 4; rt++) {
#pragma unroll
        for (int r = 0; r < 4; r++) {
            float v = bv[rt][r]; int c = bc[rt][r];
#pragma unroll
            for (int off = 8; off >= 1; off >>= 1) {
                float ov = __shfl_xor(v, off, 16); int oc = __shfl_xor(c, off, 16);
                if (ov > v || (ov == v && oc < c)) { v = ov; c = oc; }
            }
            if (col == 0) {
                int q = head * BQ + qbase + rt * 16 + quad * 4 + r;
                g_pval[part][q] = v; g_pidx[part][q] = cbase + c;
            }
        }
    }
}

// ---------------- kernel 2: merge partitions + gather + index write --------
__global__ __launch_bounds__(256) void merge_kernel(const float* __restrict__ embed,
                                                    float* __restrict__ out) {
    int id = blockIdx.x * 256 + threadIdx.x;   // m*4 + h  (m-major, coalesced idx write)
    int m = id >> 2;
    int h = id & 3;
    int q = h * BQ + m;

    float bv = g_pval[0][q]; int bc = g_pidx[0][q];
#pragma unroll
    for (int p = 1; p < NPART; p++) {
        float v = g_pval[p][q]; int c = g_pidx[p][q];
        if (v > bv || (v == bv && c < bc)) { bv = v; bc = c; }
    }

    out[QOFF + id] = (float)bc;                // embed_ind[b][n][h] as fp32 value

    int idx = bc & (CODEBOOK - 1);             // defensive in-range
    const float* src = embed + ((size_t)h * CODEBOOK + idx) * HD;
    float*       dst = out + (size_t)m * 256 + h * 64;
#pragma unroll
    for (int i = 0; i < 16; i++)               // 64 fp32, verbatim
        *reinterpret_cast<float4*>(dst + i * 4) = *reinterpret_cast<const float4*>(src + i * 4);
}

extern "C" void kernel_launch(void* const* d_in, const int* in_sizes, int n_in,
                              void* d_out, int out_size, void* d_ws, size_t ws_size,
                              hipStream_t stream) {
    const float* x     = (const float*)d_in[0];
    const float* embed = (const float*)d_in[1];
    float*       out   = (float*)d_out;

    prep_kernel <<<1024, 256, 0, stream>>>(embed);
    dist_kernel <<<4096, 64, 0, stream>>>(x);
    merge_kernel<<<128,  256, 0, stream>>>(embed, out);
}